// Round 1
// baseline (296.711 us; speedup 1.0000x reference)
//
#include <hip/hip_runtime.h>

#define WINDOW 128
#define STRIDE 16
#define NWIN   249     // (4096-128)/16 + 1
#define NF     128
#define SEQ    4096
#define LROWS  160     // LDS l-capacity: 20 chunks of 8 rows (144 used)

typedef _Float16 f16;
typedef _Float16 f16x2 __attribute__((ext_vector_type(2)));
typedef _Float16 f16x8 __attribute__((ext_vector_type(8)));
typedef float    f32x4 __attribute__((ext_vector_type(4)));
typedef float    f32x16 __attribute__((ext_vector_type(16)));

union V8 { f16x8 v8; f16x2 v2[4]; };

// Stage 8 rows x 4 features: f32 global -> (x 1/sqrt(128), f16) -> LDS transposed.
// LDS layout: lds[f * LROWS + chunk*8 + (l&7)], chunk swizzled:
//   l < 128 : chunk = (l>>3) ^ (f&15)          (chunks 0..15)
//   l >= 128: chunk = 16 + (((l>>3)&3) ^ (f&3)) (chunks 16..19)
__device__ __forceinline__ void stage8(const float* __restrict__ src, f16* lds,
                                       int f0, int l0) {
    f32x4 rows[8];
    #pragma unroll
    for (int j = 0; j < 8; ++j)
        rows[j] = *(const f32x4*)&src[(size_t)(l0 + j) * NF + f0];
    const int cbase = l0 >> 3;
    #pragma unroll
    for (int d = 0; d < 4; ++d) {
        const int f = f0 + d;
        V8 u;
        #pragma unroll
        for (int jj = 0; jj < 4; ++jj) {
            auto p = __builtin_amdgcn_cvt_pkrtz(rows[2 * jj][d], rows[2 * jj + 1][d]);
            u.v2[jj] = *(f16x2*)&p;
        }
        // fold the 1/WINDOW PCC scale in as 1/sqrt(128) on each operand (v_pk_mul_f16)
        u.v8 = u.v8 * (f16)0.08838834764831845f;
        const int ch = (l0 < 128) ? (cbase ^ (f & 15))
                                  : (16 + ((cbase & 3) ^ (f & 3)));
        *(f16x8*)&lds[f * LROWS + ch * 8] = u.v8;   // ds_write_b128
    }
}

// Compute one 128x128 Gram tile from staged rows [8*CO .. 8*CO+127] and store.
// 32x32x16 MFMA, 2x2 wave grid: wave (wr,wc) owns the 64x64 quadrant at
// (64*wr, 64*wc) as 2x2 tiles of 32x32. Fragment: lane holds row f = base+(lane&31),
// k = 16*ks + 8*(lane>>5) + j  (k-chunk = logical row-chunk clog = CO + 2*ks + h).
// C/D (m74/m101): col = lane&31, row = (reg&3) + 8*(reg>>2) + 4*(lane>>5).
// Each wave-store therefore writes two complete 128B lines (fully coalesced).
template<int CO>
__device__ __forceinline__ void compute_and_store(const f16* lds, int lane,
                                                  int wr, int wc, float* __restrict__ dst) {
    const int c15 = lane & 15;
    const int c31 = lane & 31;
    const int h   = lane >> 5;

    f32x16 acc[2][2];
    #pragma unroll
    for (int i = 0; i < 2; ++i)
        #pragma unroll
        for (int j = 0; j < 2; ++j)
            acc[i][j] = (f32x16)(0.0f);

    #pragma unroll
    for (int ks = 0; ks < 8; ++ks) {
        const int clog = CO + 2 * ks + h;
        int pc;
        if (CO == 0 || CO + 2 * ks + 1 < 16)          // compile-time after unroll
            pc = clog ^ c15;                          // main region, chunks 0..15
        else
            pc = 16 + ((clog & 3) ^ (lane & 3));      // extra region, chunks 16..19
        const int off = pc * 8;

        f16x8 af[2], bf[2];
        #pragma unroll
        for (int i = 0; i < 2; ++i)
            af[i] = *(const f16x8*)&lds[(64 * wr + 32 * i + c31) * LROWS + off];
        #pragma unroll
        for (int j = 0; j < 2; ++j)
            bf[j] = *(const f16x8*)&lds[(64 * wc + 32 * j + c31) * LROWS + off];

        #pragma unroll
        for (int i = 0; i < 2; ++i)
            #pragma unroll
            for (int j = 0; j < 2; ++j)
                acc[i][j] = __builtin_amdgcn_mfma_f32_32x32x16_f16(af[i], bf[j], acc[i][j], 0, 0, 0);
    }

    // Output never re-read: nontemporal, full-line wave stores.
    #pragma unroll
    for (int i = 0; i < 2; ++i) {
        const int R0 = 64 * wr + 32 * i + 4 * h;
        #pragma unroll
        for (int j = 0; j < 2; ++j) {
            float* dcol = dst + 64 * wc + 32 * j + c31;
            #pragma unroll
            for (int reg = 0; reg < 16; ++reg) {
                const int row = R0 + (reg & 3) + 8 * (reg >> 2);
                __builtin_nontemporal_store(acc[i][j][reg], &dcol[(size_t)row * NF]);
            }
        }
    }
}

// One block: stage 144 rows (f16, transposed, swizzled) and compute TWO
// consecutive windows (share 112 of 128 rows). 256 threads = 4 waves.
__global__ __launch_bounds__(256, 4) void pcc_kernel(const float* __restrict__ in,
                                                     float* __restrict__ out) {
    __shared__ f16 lds[NF * LROWS];   // 40 KB -> 4 blocks/CU

    // XCD-chunked bijective swizzle: 2000 blocks, 8 XCDs -> 250 contiguous
    // work items per XCD = exactly 2 batches = 4 MB input = one XCD's L2.
    const int lin = blockIdx.x + 125 * blockIdx.y;
    const int swz = (lin & 7) * 250 + (lin >> 3);
    const int wp  = swz % 125;        // window pair 0..124
    const int b   = swz / 125;        // batch 0..15

    const int tid = threadIdx.x;
    const bool full = (wp < 124);     // wp==124 handles only window 248
    const int stage_base = full ? 32 * wp : (SEQ - 144);   // 3952

    const float* src = in + ((size_t)b * SEQ + stage_base) * NF;
    const int f0 = 4 * (tid & 31);
    const int lh = tid >> 5;

    stage8(src, lds, f0, 8 * lh);            // rows 0..63
    stage8(src, lds, f0, 64 + 8 * lh);       // rows 64..127
    if (tid < 64)                            // wave 0 only: rows 128..143
        stage8(src, lds, f0, 128 + 8 * lh);
    __syncthreads();

    const int lane = tid & 63;
    const int wid  = tid >> 6;
    const int wr   = wid >> 1;
    const int wc   = wid & 1;

    float* outb = out + (size_t)b * NWIN * (NF * NF);
    if (full)
        compute_and_store<0>(lds, lane, wr, wc, outb + (size_t)(2 * wp) * (NF * NF));
    const int w1 = full ? (2 * wp + 1) : (NWIN - 1);
    compute_and_store<2>(lds, lane, wr, wc, outb + (size_t)w1 * (NF * NF));
}

extern "C" void kernel_launch(void* const* d_in, const int* in_sizes, int n_in,
                              void* d_out, int out_size, void* d_ws, size_t ws_size,
                              hipStream_t stream) {
    (void)in_sizes; (void)n_in; (void)d_ws; (void)ws_size; (void)out_size;
    const float* in = (const float*)d_in[0];
    float* out = (float*)d_out;
    dim3 grid(125, 16);
    pcc_kernel<<<grid, dim3(256, 1, 1), 0, stream>>>(in, out);
}

// Round 2
// 296.566 us; speedup vs baseline: 1.0005x; 1.0005x over previous
//
#include <hip/hip_runtime.h>

#define WINDOW 128
#define STRIDE 16
#define NWIN   249     // (4096-128)/16 + 1
#define NF     128
#define SEQ    4096
#define LROWS  160     // ring capacity: 20 chunks of 8 rows
#define NSTRIP 63      // per batch: 62 full strips (4 windows) + 1 tail (1 window)

typedef _Float16 f16;
typedef _Float16 f16x2 __attribute__((ext_vector_type(2)));
typedef _Float16 f16x4 __attribute__((ext_vector_type(4)));
typedef _Float16 f16x8 __attribute__((ext_vector_type(8)));
typedef float    f32x4 __attribute__((ext_vector_type(4)));
typedef float    f32x16 __attribute__((ext_vector_type(16)));

union V8 { f16x8 v8; f16x2 v2[4]; };
union V4 { f16x4 v4; f16x2 v2[2]; };

// LDS layout: f-major, lds[f * LROWS + phys_row]; rows grouped in chunks of 8.
// Bank swizzle: physical chunk = (ch & ~3) | ((ch ^ (f>>1)) & 3)  (bijective per f,
// spreads fragment reads to 8 bank-starts = 4-way aliasing, same as prior kernel).

// Stage 8 rows x 4 features (one chunk): f32 global -> (x 1/sqrt(128), f16) -> LDS.
__device__ __forceinline__ void stage8(const float* __restrict__ src, f16* lds,
                                       int f0, int l0 /* rel row, chunk-aligned */) {
    f32x4 rows[8];
    #pragma unroll
    for (int j = 0; j < 8; ++j)
        rows[j] = *(const f32x4*)&src[(size_t)(l0 + j) * NF + f0];
    const int ch = l0 >> 3;
    #pragma unroll
    for (int d = 0; d < 4; ++d) {
        const int f = f0 + d;
        V8 u;
        #pragma unroll
        for (int jj = 0; jj < 4; ++jj) {
            auto p = __builtin_amdgcn_cvt_pkrtz(rows[2 * jj][d], rows[2 * jj + 1][d]);
            u.v2[jj] = *(f16x2*)&p;
        }
        u.v8 = u.v8 * (f16)0.08838834764831845f;   // fold 1/WINDOW as 1/sqrt(128)
        const int pch = (ch & ~3) | ((ch ^ (f >> 1)) & 3);
        *(f16x8*)&lds[f * LROWS + pch * 8] = u.v8;  // ds_write_b128
    }
}

// T14 split staging of the incoming 32 rows: issue-early (into regs) ...
__device__ __forceinline__ void load4(const float* __restrict__ src, f32x4 r[4],
                                      int f0, int l0) {
    #pragma unroll
    for (int j = 0; j < 4; ++j)
        r[j] = *(const f32x4*)&src[(size_t)(l0 + j) * NF + f0];
}

// ... write-late (regs -> ring slots; relrow 144..175 -> phys chunks {18,19,0,1}).
__device__ __forceinline__ void write4(f16* lds, const f32x4 r[4], int f0, int relrow) {
    const int phys = relrow - (relrow >= LROWS ? LROWS : 0);
    const int ch = phys >> 3;
    const int sub = phys & 7;          // 0 or 4
    #pragma unroll
    for (int d = 0; d < 4; ++d) {
        const int f = f0 + d;
        V4 u;
        {
            auto p0 = __builtin_amdgcn_cvt_pkrtz(r[0][d], r[1][d]);
            auto p1 = __builtin_amdgcn_cvt_pkrtz(r[2][d], r[3][d]);
            u.v2[0] = *(f16x2*)&p0;
            u.v2[1] = *(f16x2*)&p1;
        }
        u.v4 = u.v4 * (f16)0.08838834764831845f;
        const int pch = (ch & ~3) | ((ch ^ (f >> 1)) & 3);
        *(f16x4*)&lds[f * LROWS + pch * 8 + sub] = u.v4;   // ds_write_b64
    }
}

// One 128x128 Gram tile for window wi (rel rows 16*wi .. 16*wi+127 in the ring).
// 32x32x16 MFMA, 2x2 wave grid; lane holds row f = base+(lane&31), k = 16ks+8h+j.
// C/D: col = lane&31, row = (reg&3) + 8*(reg>>2) + 4*h  (verified rounds 0/1).
__device__ __forceinline__ void compute_store(const f16* lds, int lane, int wr, int wc,
                                              int wi, float* __restrict__ dst) {
    const int c31 = lane & 31;
    const int h   = lane >> 5;
    const int q2  = c31 >> 1;          // (f>>1)&3 == (c31>>1)&3 for all 4 fragments

    f32x16 acc[2][2];
    #pragma unroll
    for (int i = 0; i < 2; ++i)
        #pragma unroll
        for (int j = 0; j < 2; ++j)
            acc[i][j] = (f32x16)(0.0f);

    const int fa0 = (64 * wr + c31) * LROWS;
    const int fa1 = (64 * wr + 32 + c31) * LROWS;
    const int fb0 = (64 * wc + c31) * LROWS;
    const int fb1 = (64 * wc + 32 + c31) * LROWS;

    #pragma unroll
    for (int ks = 0; ks < 8; ++ks) {
        const int chlog = 2 * wi + 2 * ks + h;
        const int ch = chlog - (chlog >= 20 ? 20 : 0);     // ring wrap (wi=3 only)
        const int off = ((ch & ~3) | ((ch ^ q2) & 3)) * 8;

        const f16x8 a0 = *(const f16x8*)&lds[fa0 + off];
        const f16x8 a1 = *(const f16x8*)&lds[fa1 + off];
        const f16x8 b0 = *(const f16x8*)&lds[fb0 + off];
        const f16x8 b1 = *(const f16x8*)&lds[fb1 + off];

        acc[0][0] = __builtin_amdgcn_mfma_f32_32x32x16_f16(a0, b0, acc[0][0], 0, 0, 0);
        acc[0][1] = __builtin_amdgcn_mfma_f32_32x32x16_f16(a0, b1, acc[0][1], 0, 0, 0);
        acc[1][0] = __builtin_amdgcn_mfma_f32_32x32x16_f16(a1, b0, acc[1][0], 0, 0, 0);
        acc[1][1] = __builtin_amdgcn_mfma_f32_32x32x16_f16(a1, b1, acc[1][1], 0, 0, 0);
    }

    // Full-line nontemporal wave stores (output never re-read; keeps L2 for input).
    #pragma unroll
    for (int i = 0; i < 2; ++i) {
        const int R0 = 64 * wr + 32 * i + 4 * h;
        #pragma unroll
        for (int j = 0; j < 2; ++j) {
            float* dcol = dst + 64 * wc + 32 * j + c31;
            #pragma unroll
            for (int reg = 0; reg < 16; ++reg) {
                const int row = R0 + (reg & 3) + 8 * (reg >> 2);
                __builtin_nontemporal_store(acc[i][j][reg], &dcol[(size_t)row * NF]);
            }
        }
    }
}

// One block = one strip of 4 consecutive windows (tail strip: 1 window).
// Ring schedule (rel rows, phys = rel mod 160):
//   stage rel 0..143 -> chunks 0..17;  __syncthreads
//   issue loads rel 144..175 (regs);   compute w0 (chunks 0..15)
//   raw s_barrier (releases chunks 0,1; does NOT drain in-flight stores)
//   write4 -> chunks {18,19,0,1};      compute w1 (chunks 2..17, disjoint)
//   lgkmcnt(0) + raw s_barrier (writes visible)
//   compute w2 (chunks 4..19);         compute w3 (chunks 6..19,0,1)
__global__ __launch_bounds__(256, 4) void pcc_kernel(const float* __restrict__ in,
                                                     float* __restrict__ out) {
    __shared__ f16 lds[NF * LROWS];    // 40 KB -> 4 blocks/CU

    // XCD-chunked bijective swizzle: 1008 blocks = 8 XCDs x 126.
    // Consecutive work items on one XCD = consecutive strips (112-row overlap -> L2).
    const int lin  = blockIdx.x + NSTRIP * blockIdx.y;
    const int swzb = (lin & 7) * 126 + (lin >> 3);
    const int b    = swzb / NSTRIP;
    const int s    = swzb - b * NSTRIP;

    const int tid = threadIdx.x;
    const bool full = (s < NSTRIP - 1);
    const int base = 64 * s;                       // tail: 64*62 = 3968, 128 rows
    const float* src = in + ((size_t)b * SEQ + base) * NF;
    const int f0 = 4 * (tid & 31);
    const int lh = tid >> 5;

    stage8(src, lds, f0, 8 * lh);                  // rel 0..63
    stage8(src, lds, f0, 64 + 8 * lh);             // rel 64..127
    if (full && tid < 64)
        stage8(src, lds, f0, 128 + 8 * lh);        // rel 128..143
    __syncthreads();

    const int lane = tid & 63;
    const int wid  = tid >> 6;
    const int wr   = wid >> 1;
    const int wc   = wid & 1;

    float* dst0 = out + (size_t)b * NWIN * (NF * NF) + (size_t)(4 * s) * (NF * NF);

    if (!full) {                                   // tail: single window 248
        compute_store(lds, lane, wr, wc, 0, dst0);
        return;
    }

    // Issue incoming loads early: rel 144..175 (4 rows x 4 feats per thread).
    f32x4 hold[4];
    const int r0 = 4 * lh;                         // 0..28
    load4(src, hold, f0, 144 + r0);

    compute_store(lds, lane, wr, wc, 0, dst0);

    __builtin_amdgcn_sched_barrier(0);
    __builtin_amdgcn_s_barrier();                  // release chunks 0,1 (no vm drain)
    __builtin_amdgcn_sched_barrier(0);

    write4(lds, hold, f0, 144 + r0);               // chunks {18,19,0,1}

    compute_store(lds, lane, wr, wc, 1, dst0 + (size_t)(NF * NF));

    asm volatile("s_waitcnt lgkmcnt(0)" ::: "memory");
    __builtin_amdgcn_sched_barrier(0);
    __builtin_amdgcn_s_barrier();                  // incoming rows visible
    __builtin_amdgcn_sched_barrier(0);

    compute_store(lds, lane, wr, wc, 2, dst0 + (size_t)2 * (NF * NF));
    compute_store(lds, lane, wr, wc, 3, dst0 + (size_t)3 * (NF * NF));
}

extern "C" void kernel_launch(void* const* d_in, const int* in_sizes, int n_in,
                              void* d_out, int out_size, void* d_ws, size_t ws_size,
                              hipStream_t stream) {
    (void)in_sizes; (void)n_in; (void)d_ws; (void)ws_size; (void)out_size;
    const float* in = (const float*)d_in[0];
    float* out = (float*)d_out;
    dim3 grid(NSTRIP, 16);
    pcc_kernel<<<grid, dim3(256, 1, 1), 0, stream>>>(in, out);
}